// Round 1
// baseline (30.185 us; speedup 1.0000x reference)
//
#include <hip/hip_runtime.h>
#include <hip/hip_bf16.h>

// MedianPool2d: 3x3 median, stride 1, reflect pad 1.
// x: [N=16, C=3, H=512, W=512] fp32 -> out same shape fp32.
// One thread computes 4 consecutive output pixels in a row (float4 I/O).

#define PIX_SORT(a, b) { float t_ = fminf(a, b); b = fmaxf(a, b); a = t_; }

__global__ __launch_bounds__(256) void median_pool_3x3_kernel(
    const float* __restrict__ x, float* __restrict__ out, int total_quads) {
    constexpr int H = 512;
    constexpr int W = 512;
    constexpr int WQ = W / 4;  // 128 quads per row

    int idx = blockIdx.x * 256 + threadIdx.x;
    if (idx >= total_quads) return;

    int wq   = idx & (WQ - 1);      // quad index within the row
    int rest = idx >> 7;            // = nc * H + h
    int h    = rest & (H - 1);
    int w0   = wq * 4;

    const float* base = x + (size_t)(rest - h) * W;  // start of this (n,c) image

    // reflect-padded row indices
    int hm = (h == 0)       ? 1       : h - 1;
    int hp = (h == H - 1)   ? H - 2   : h + 1;
    int rows[3] = {hm, h, hp};

    // r[i][0..5] = {left, v0, v1, v2, v3, right} for row i
    float r[3][6];
    int wl = (w0 == 0)     ? 1     : w0 - 1;   // reflect left
    int wr = (w0 + 4 == W) ? W - 2 : w0 + 4;   // reflect right

    #pragma unroll
    for (int i = 0; i < 3; ++i) {
        const float* p = base + (size_t)rows[i] * W;
        float4 v = *reinterpret_cast<const float4*>(p + w0);
        r[i][0] = p[wl];
        r[i][1] = v.x; r[i][2] = v.y; r[i][3] = v.z; r[i][4] = v.w;
        r[i][5] = p[wr];
    }

    float o[4];
    #pragma unroll
    for (int j = 0; j < 4; ++j) {
        float p0 = r[0][j], p1 = r[0][j + 1], p2 = r[0][j + 2];
        float p3 = r[1][j], p4 = r[1][j + 1], p5 = r[1][j + 2];
        float p6 = r[2][j], p7 = r[2][j + 1], p8 = r[2][j + 2];

        // opt_med9: 19 compare-exchanges, exact median in p4
        PIX_SORT(p1, p2); PIX_SORT(p4, p5); PIX_SORT(p7, p8);
        PIX_SORT(p0, p1); PIX_SORT(p3, p4); PIX_SORT(p6, p7);
        PIX_SORT(p1, p2); PIX_SORT(p4, p5); PIX_SORT(p7, p8);
        PIX_SORT(p0, p3); PIX_SORT(p5, p8); PIX_SORT(p4, p7);
        PIX_SORT(p3, p6); PIX_SORT(p1, p4); PIX_SORT(p2, p5);
        PIX_SORT(p4, p7); PIX_SORT(p4, p2); PIX_SORT(p6, p4);
        PIX_SORT(p4, p2);

        o[j] = p4;
    }

    float4 ov = make_float4(o[0], o[1], o[2], o[3]);
    *reinterpret_cast<float4*>(out + (size_t)rest * W + w0) = ov;
}

extern "C" void kernel_launch(void* const* d_in, const int* in_sizes, int n_in,
                              void* d_out, int out_size, void* d_ws, size_t ws_size,
                              hipStream_t stream) {
    const float* x = (const float*)d_in[0];
    float* out = (float*)d_out;
    int total_quads = in_sizes[0] / 4;  // 16*3*512*512 / 4 = 3,145,728
    int blocks = (total_quads + 255) / 256;
    median_pool_3x3_kernel<<<blocks, 256, 0, stream>>>(x, out, total_quads);
}

// Round 2
// 22.936 us; speedup vs baseline: 1.3161x; 1.3161x over previous
//
#include <hip/hip_runtime.h>
#include <hip/hip_bf16.h>

// MedianPool2d: 3x3 median, stride 1, reflect pad 1.
// x: [16, 3, 512, 512] fp32 -> out same shape fp32.
// One thread computes a 4x4 output tile (float4 I/O, 6 input rows).
// median9 = med3( max3(col mins), med3(col meds), min3(col maxes) ).

__global__ __launch_bounds__(256) void median_pool_3x3_t4x4(
    const float* __restrict__ x, float* __restrict__ out) {
    constexpr int H = 512;
    constexpr int W = 512;

    int idx = blockIdx.x * 256 + threadIdx.x;
    int twq = idx & 127;       // w-tile index (128 per row)
    int t   = idx >> 7;
    int th  = t & 127;         // h-tile index (128 per image)
    int img = t >> 7;          // n*c image index (0..47)

    int h0 = th * 4;
    int w0 = twq * 4;
    const float* base = x + (size_t)img * (H * W);

    int wl = (w0 == 0)     ? 1     : w0 - 1;   // reflect left
    int wr = (w0 + 4 == W) ? W - 2 : w0 + 4;   // reflect right

    // rb[k][0..5] = {left, v0, v1, v2, v3, right} for input rows h0-1 .. h0+4
    float rb[6][6];
    #pragma unroll
    for (int k = 0; k < 6; ++k) {
        int h = h0 - 1 + k;
        h = (h < 0) ? 1 : ((h >= H) ? (2 * H - 2 - h) : h);  // reflect
        const float* p = base + (size_t)h * W;
        float4 v = *reinterpret_cast<const float4*>(p + w0);
        rb[k][0] = p[wl];
        rb[k][1] = v.x; rb[k][2] = v.y; rb[k][3] = v.z; rb[k][4] = v.w;
        rb[k][5] = p[wr];
    }

    float* op = out + (size_t)(img * H + h0) * W + w0;
    #pragma unroll
    for (int r = 0; r < 4; ++r) {
        float lo[6], mi[6], hi[6];
        #pragma unroll
        for (int c = 0; c < 6; ++c) {
            float a = rb[r][c], b = rb[r + 1][c], d = rb[r + 2][c];
            lo[c] = fminf(fminf(a, b), d);                 // v_min3_f32
            hi[c] = fmaxf(fmaxf(a, b), d);                 // v_max3_f32
            mi[c] = __builtin_amdgcn_fmed3f(a, b, d);      // v_med3_f32
        }
        float o[4];
        #pragma unroll
        for (int j = 0; j < 4; ++j) {
            float mx = fmaxf(fmaxf(lo[j], lo[j + 1]), lo[j + 2]);
            float mn = fminf(fminf(hi[j], hi[j + 1]), hi[j + 2]);
            float md = __builtin_amdgcn_fmed3f(mi[j], mi[j + 1], mi[j + 2]);
            o[j] = __builtin_amdgcn_fmed3f(mx, md, mn);
        }
        *reinterpret_cast<float4*>(op + (size_t)r * W) =
            make_float4(o[0], o[1], o[2], o[3]);
    }
}

extern "C" void kernel_launch(void* const* d_in, const int* in_sizes, int n_in,
                              void* d_out, int out_size, void* d_ws, size_t ws_size,
                              hipStream_t stream) {
    const float* x = (const float*)d_in[0];
    float* out = (float*)d_out;
    int total_tiles = in_sizes[0] / 16;          // 786432 threads (4x4 px each)
    int blocks = total_tiles / 256;              // 3072, exact
    median_pool_3x3_t4x4<<<blocks, 256, 0, stream>>>(x, out);
}

// Round 3
// 21.660 us; speedup vs baseline: 1.3936x; 1.0589x over previous
//
#include <hip/hip_runtime.h>
#include <hip/hip_bf16.h>

// MedianPool2d: 3x3 median, stride 1, reflect pad 1.
// x: [16, 3, 512, 512] fp32 -> out same shape fp32.
// One thread computes an 8x4 output tile (float4 I/O, 10 input rows,
// rolling 3-row stats window). XCD-aware block swizzle for halo L2 reuse.
// median9 = med3( max3(row-mins), med3(row-meds), min3(row-maxes) ).

__global__ __launch_bounds__(256) void median_pool_3x3_t8x4(
    const float* __restrict__ x, float* __restrict__ out) {
    constexpr int H = 512;
    constexpr int W = 512;
    constexpr int TH = 8;                 // output rows per thread

    // XCD-aware swizzle: 1536 blocks, 8 XCDs, 192 blocks each (bijective).
    int b   = blockIdx.x;
    int wb  = (b & 7) * 192 + (b >> 3);
    int idx = wb * 256 + threadIdx.x;

    int twq = idx & 127;                  // w-tile (128 per row)
    int t   = idx >> 7;
    int th  = t & 63;                     // h-tile (64 per image)
    int img = t >> 6;                     // n*c image (0..47)

    int h0 = th * TH;
    int w0 = twq * 4;
    const float* base = x + (size_t)img * (H * W);

    int wl = (w0 == 0)     ? 1     : w0 - 1;   // reflect left
    int wr = (w0 + 4 == W) ? W - 2 : w0 + 4;   // reflect right

    // rolling per-row horizontal stats: slot = input_row % 3
    float slo[3][4], smd[3][4], shi[3][4];

#define LOADROW(K, SLOT)                                                     \
    {                                                                        \
        int h_ = h0 - 1 + (K);                                               \
        h_ = (h_ < 0) ? 1 : ((h_ >= H) ? (2 * H - 2 - h_) : h_);             \
        const float* p_ = base + (size_t)h_ * W;                             \
        float4 v_ = *reinterpret_cast<const float4*>(p_ + w0);               \
        float a0 = p_[wl], a1 = v_.x, a2 = v_.y, a3 = v_.z, a4 = v_.w,       \
              a5 = p_[wr];                                                   \
        slo[SLOT][0] = fminf(fminf(a0, a1), a2);                             \
        slo[SLOT][1] = fminf(fminf(a1, a2), a3);                             \
        slo[SLOT][2] = fminf(fminf(a2, a3), a4);                             \
        slo[SLOT][3] = fminf(fminf(a3, a4), a5);                             \
        smd[SLOT][0] = __builtin_amdgcn_fmed3f(a0, a1, a2);                  \
        smd[SLOT][1] = __builtin_amdgcn_fmed3f(a1, a2, a3);                  \
        smd[SLOT][2] = __builtin_amdgcn_fmed3f(a2, a3, a4);                  \
        smd[SLOT][3] = __builtin_amdgcn_fmed3f(a3, a4, a5);                  \
        shi[SLOT][0] = fmaxf(fmaxf(a0, a1), a2);                             \
        shi[SLOT][1] = fmaxf(fmaxf(a1, a2), a3);                             \
        shi[SLOT][2] = fmaxf(fmaxf(a2, a3), a4);                             \
        shi[SLOT][3] = fmaxf(fmaxf(a3, a4), a5);                             \
    }

    LOADROW(0, 0);
    LOADROW(1, 1);

    float* op = out + (size_t)(img * H + h0) * W + w0;

    #pragma unroll
    for (int r = 0; r < TH; ++r) {
        LOADROW(r + 2, (r + 2) % 3);
        const int s0 = r % 3, s1 = (r + 1) % 3, s2 = (r + 2) % 3;
        float o[4];
        #pragma unroll
        for (int j = 0; j < 4; ++j) {
            float mx = fmaxf(fmaxf(slo[s0][j], slo[s1][j]), slo[s2][j]);
            float md = __builtin_amdgcn_fmed3f(smd[s0][j], smd[s1][j], smd[s2][j]);
            float mn = fminf(fminf(shi[s0][j], shi[s1][j]), shi[s2][j]);
            o[j] = __builtin_amdgcn_fmed3f(mx, md, mn);
        }
        *reinterpret_cast<float4*>(op + (size_t)r * W) =
            make_float4(o[0], o[1], o[2], o[3]);
    }
#undef LOADROW
}

extern "C" void kernel_launch(void* const* d_in, const int* in_sizes, int n_in,
                              void* d_out, int out_size, void* d_ws, size_t ws_size,
                              hipStream_t stream) {
    const float* x = (const float*)d_in[0];
    float* out = (float*)d_out;
    int total_threads = in_sizes[0] / 32;        // 8x4 px per thread -> 393216
    int blocks = total_threads / 256;            // 1536, exact (divisible by 8)
    median_pool_3x3_t8x4<<<blocks, 256, 0, stream>>>(x, out);
}